// Round 2
// baseline (1132.038 us; speedup 1.0000x reference)
//
#include <hip/hip_runtime.h>
#include <cstdint>
#include <cstddef>

#define NN 100000   // N_NODES
#define D  128

// ---------------- utility ----------------
__global__ void zero_int_kernel(int* __restrict__ p, int n) {
    int i = blockIdx.x * blockDim.x + threadIdx.x;
    if (i < n) p[i] = 0;
}

// deg[dst]++ histogram
__global__ void hist_kernel(const int* __restrict__ dst, int E, int* __restrict__ deg) {
    int i = blockIdx.x * blockDim.x + threadIdx.x;
    int stride = gridDim.x * blockDim.x;
    for (int e = i; e < E; e += stride)
        atomicAdd(&deg[dst[e]], 1);
}

__global__ void dinv_kernel(const int* __restrict__ deg, float* __restrict__ dinv, int n) {
    int i = blockIdx.x * blockDim.x + threadIdx.x;
    if (i < n) {
        int d = deg[i];
        dinv[i] = (d > 0) ? (1.0f / sqrtf((float)d)) : 0.0f;
    }
}

// ---------------- prefix scan (3 stages) ----------------
__global__ __launch_bounds__(1024) void scan1_kernel(const int* __restrict__ deg, int n,
                                                     int* __restrict__ excl,
                                                     int* __restrict__ bsums) {
    __shared__ int sm[1024];
    int tid = threadIdx.x;
    int g = blockIdx.x * 1024 + tid;
    int v = (g < n) ? deg[g] : 0;
    sm[tid] = v;
    __syncthreads();
    for (int off = 1; off < 1024; off <<= 1) {
        int t = (tid >= off) ? sm[tid - off] : 0;
        __syncthreads();
        sm[tid] += t;
        __syncthreads();
    }
    if (g < n) excl[g] = sm[tid] - v;
    if (tid == 1023) bsums[blockIdx.x] = sm[1023];
}

__global__ void scan2_kernel(int* __restrict__ bsums, int nb) {
    __shared__ int sm[128];
    int tid = threadIdx.x;
    int v = (tid < nb) ? bsums[tid] : 0;
    sm[tid] = v;
    __syncthreads();
    for (int off = 1; off < 128; off <<= 1) {
        int t = (tid >= off) ? sm[tid - off] : 0;
        __syncthreads();
        sm[tid] += t;
        __syncthreads();
    }
    if (tid < nb) bsums[tid] = sm[tid] - v;   // exclusive
    if (tid == 127) bsums[nb] = sm[127];      // grand total (== E)
}

__global__ void scan3_kernel(int* __restrict__ rp, const int* __restrict__ bsums,
                             int n, int* __restrict__ cursor, int nb) {
    int g = blockIdx.x * blockDim.x + threadIdx.x;
    if (g < n) {
        int r = rp[g] + bsums[g >> 10];
        rp[g] = r;
        cursor[g] = r;
    }
    if (g == 0) rp[n] = bsums[nb];
}

// bucket-fill: src grouped by dst
__global__ void fill_kernel(const int* __restrict__ src, const int* __restrict__ dst, int E,
                            int* __restrict__ cursor, int* __restrict__ ssorted) {
    int i = blockIdx.x * blockDim.x + threadIdx.x;
    int stride = gridDim.x * blockDim.x;
    for (int e = i; e < E; e += stride) {
        int d = dst[e];
        int p = atomicAdd(&cursor[d], 1);
        ssorted[p] = src[e];
    }
}

// ---------------- GEMM: C[N,128] = A[N,128] @ W[128,128] + bias ----------------
__global__ __launch_bounds__(256) void gemm_kernel(const float* __restrict__ A,
                                                   const float* __restrict__ W,
                                                   const float* __restrict__ bias,
                                                   float* __restrict__ C) {
    __shared__ float As[32][128];
    int tid = threadIdx.x;
    size_t r0 = (size_t)blockIdx.x * 32;

    const float4* Ap = (const float4*)(A + r0 * D);
    float4* Asp = (float4*)&As[0][0];
#pragma unroll
    for (int i = 0; i < 4; ++i) Asp[tid + 256 * i] = Ap[tid + 256 * i];
    __syncthreads();

    int c4 = tid & 31;   // float4 column group
    int rb = tid >> 5;   // 0..7
    float4 bv = ((const float4*)bias)[c4];
    float4 acc[4];
#pragma unroll
    for (int j = 0; j < 4; ++j) acc[j] = bv;

    for (int k4 = 0; k4 < 32; ++k4) {
        float4 w0 = ((const float4*)(W + (k4 * 4 + 0) * D))[c4];
        float4 w1 = ((const float4*)(W + (k4 * 4 + 1) * D))[c4];
        float4 w2 = ((const float4*)(W + (k4 * 4 + 2) * D))[c4];
        float4 w3 = ((const float4*)(W + (k4 * 4 + 3) * D))[c4];
#pragma unroll
        for (int j = 0; j < 4; ++j) {
            float4 xv = *(const float4*)(&As[rb + 8 * j][k4 * 4]);
            acc[j].x += xv.x * w0.x + xv.y * w1.x + xv.z * w2.x + xv.w * w3.x;
            acc[j].y += xv.x * w0.y + xv.y * w1.y + xv.z * w2.y + xv.w * w3.y;
            acc[j].z += xv.x * w0.z + xv.y * w1.z + xv.z * w2.z + xv.w * w3.z;
            acc[j].w += xv.x * w0.w + xv.y * w1.w + xv.z * w2.w + xv.w * w3.w;
        }
    }
#pragma unroll
    for (int j = 0; j < 4; ++j)
        *((float4*)(C + (r0 + rb + 8 * j) * D) + c4) = acc[j];
}

// ---------------- gather-sum conv ----------------
// out[v] = (base ? base[v] : 0) + sum_{e in CSR[v]} dinv[src]*dinv[v]*s * h[src]
// one wave per node; lane owns float2 of the 128-wide row.
// Edge indices + dinv[src] are batch-loaded 64-at-a-time (coalesced) and
// broadcast per-edge via __shfl; row loads unrolled x4 for MLP.
__global__ __launch_bounds__(256) void gather_kernel(const float* __restrict__ h,
                                                     const int* __restrict__ ssorted,
                                                     const int* __restrict__ rp,
                                                     const float* __restrict__ dinv,
                                                     const float* __restrict__ base,
                                                     float* __restrict__ out,
                                                     const int* __restrict__ sp, int n) {
    int v = blockIdx.x * 4 + (threadIdx.x >> 6);
    if (v >= n) return;
    int lane = threadIdx.x & 63;
    float sf = (float)sp[0];
    int beg = rp[v], end = rp[v + 1];
    float dv = dinv[v] * sf;
    float ax = 0.0f, ay = 0.0f;

    int e = beg;
    while (e < end) {
        int cnt = end - e;
        if (cnt > 64) cnt = 64;
        // cooperative batch load of indices + per-src norm (coalesced)
        int   idx = (lane < cnt) ? ssorted[e + lane] : 0;
        float wsc = (lane < cnt) ? dinv[idx] * dv : 0.0f;

        int j = 0;
        for (; j + 3 < cnt; j += 4) {
            int s0 = __shfl(idx, j + 0), s1 = __shfl(idx, j + 1);
            int s2 = __shfl(idx, j + 2), s3 = __shfl(idx, j + 3);
            float w0 = __shfl(wsc, j + 0), w1 = __shfl(wsc, j + 1);
            float w2 = __shfl(wsc, j + 2), w3 = __shfl(wsc, j + 3);
            float2 h0 = *(const float2*)(h + (size_t)s0 * D + lane * 2);
            float2 h1 = *(const float2*)(h + (size_t)s1 * D + lane * 2);
            float2 h2 = *(const float2*)(h + (size_t)s2 * D + lane * 2);
            float2 h3 = *(const float2*)(h + (size_t)s3 * D + lane * 2);
            ax += h0.x * w0 + h1.x * w1 + h2.x * w2 + h3.x * w3;
            ay += h0.y * w0 + h1.y * w1 + h2.y * w2 + h3.y * w3;
        }
        for (; j < cnt; ++j) {
            int   s = __shfl(idx, j);
            float w = __shfl(wsc, j);
            float2 hv = *(const float2*)(h + (size_t)s * D + lane * 2);
            ax += hv.x * w;
            ay += hv.y * w;
        }
        e += cnt;
    }

    size_t o = (size_t)v * D + lane * 2;
    if (base) {
        float2 b2 = *(const float2*)(base + o);
        ax += b2.x;
        ay += b2.y;
    }
    *(float2*)(out + o) = make_float2(ax, ay);
}

// ---------------- launch ----------------
extern "C" void kernel_launch(void* const* d_in, const int* in_sizes, int n_in,
                              void* d_out, int out_size, void* d_ws, size_t ws_size,
                              hipStream_t stream) {
    const float* X  = (const float*)d_in[0];
    const float* W1 = (const float*)d_in[1];
    const float* b1 = (const float*)d_in[2];
    const float* W2 = (const float*)d_in[3];
    const float* b2 = (const float*)d_in[4];
    const int*   ei = (const int*)d_in[5];
    const int*   sp = (const int*)d_in[6];

    const int N = NN;
    const int E = in_sizes[5] / 2;
    const int* src = ei;
    const int* dst = ei + E;

    char* ws = (char*)d_ws;
    size_t off = 0;
    auto alloc = [&](size_t bytes) -> void* {
        void* p = ws + off;
        off += (bytes + 255) / 256 * 256;
        return p;
    };
    int*   deg    = (int*)  alloc((size_t)N * 4);
    float* dinv   = (float*)alloc((size_t)N * 4);
    int*   rp     = (int*)  alloc((size_t)(N + 1) * 4);
    int*   cursor = (int*)  alloc((size_t)N * 4);
    int*   bsums  = (int*)  alloc(256 * 4);
    int*   ssort  = (int*)  alloc((size_t)E * 4);
    float* h      = (float*)alloc((size_t)N * D * 4);
    float* x      = (float*)alloc((size_t)N * D * 4);
    float* out    = (float*)d_out;

    const int nb = (N + 1023) / 1024;  // 98

    zero_int_kernel<<<(N + 255) / 256, 256, 0, stream>>>(deg, N);
    hist_kernel<<<2048, 256, 0, stream>>>(dst, E, deg);
    dinv_kernel<<<(N + 255) / 256, 256, 0, stream>>>(deg, dinv, N);
    scan1_kernel<<<nb, 1024, 0, stream>>>(deg, N, rp, bsums);
    scan2_kernel<<<1, 128, 0, stream>>>(bsums, nb);
    scan3_kernel<<<(N + 255) / 256, 256, 0, stream>>>(rp, bsums, N, cursor, nb);
    fill_kernel<<<2048, 256, 0, stream>>>(src, dst, E, cursor, ssort);

    gemm_kernel<<<N / 32, 256, 0, stream>>>(X, W1, b1, h);
    gather_kernel<<<(N + 3) / 4, 256, 0, stream>>>(h, ssort, rp, dinv, nullptr, x, sp, N);
    gemm_kernel<<<N / 32, 256, 0, stream>>>(x, W2, b2, h);
    gather_kernel<<<(N + 3) / 4, 256, 0, stream>>>(h, ssort, rp, dinv, x, out, sp, N);
}

// Round 5
// 963.827 us; speedup vs baseline: 1.1745x; 1.1745x over previous
//
#include <hip/hip_runtime.h>
#include <cstdint>
#include <cstddef>

#define NN 100000   // N_NODES
#define D  128
#define NREG 8          // scatter regions == XCDs
#define REG_NODES 12500 // NN / NREG

// ---------------- utility ----------------
__global__ void zero_int_kernel(int* __restrict__ p, int n) {
    int i = blockIdx.x * blockDim.x + threadIdx.x;
    if (i < n) p[i] = 0;
}

// deg[dst]++ histogram (atomics only — no scattered plain stores, so no
// writeback-amp problem like fill had; keep simple)
__global__ void hist_kernel(const int* __restrict__ dst, int E, int* __restrict__ deg) {
    int i = blockIdx.x * blockDim.x + threadIdx.x;
    int stride = gridDim.x * blockDim.x;
    for (int e = i; e < E; e += stride)
        atomicAdd(&deg[dst[e]], 1);
}

__global__ void dinv_kernel(const int* __restrict__ deg, float* __restrict__ dinv, int n) {
    int i = blockIdx.x * blockDim.x + threadIdx.x;
    if (i < n) {
        int d = deg[i];
        dinv[i] = (d > 0) ? (1.0f / sqrtf((float)d)) : 0.0f;
    }
}

// ---------------- prefix scan (3 stages) ----------------
__global__ __launch_bounds__(1024) void scan1_kernel(const int* __restrict__ deg, int n,
                                                     int* __restrict__ excl,
                                                     int* __restrict__ bsums) {
    __shared__ int sm[1024];
    int tid = threadIdx.x;
    int g = blockIdx.x * 1024 + tid;
    int v = (g < n) ? deg[g] : 0;
    sm[tid] = v;
    __syncthreads();
    for (int off = 1; off < 1024; off <<= 1) {
        int t = (tid >= off) ? sm[tid - off] : 0;
        __syncthreads();
        sm[tid] += t;
        __syncthreads();
    }
    if (g < n) excl[g] = sm[tid] - v;
    if (tid == 1023) bsums[blockIdx.x] = sm[1023];
}

__global__ void scan2_kernel(int* __restrict__ bsums, int nb) {
    __shared__ int sm[128];
    int tid = threadIdx.x;
    int v = (tid < nb) ? bsums[tid] : 0;
    sm[tid] = v;
    __syncthreads();
    for (int off = 1; off < 128; off <<= 1) {
        int t = (tid >= off) ? sm[tid - off] : 0;
        __syncthreads();
        sm[tid] += t;
        __syncthreads();
    }
    if (tid < nb) bsums[tid] = sm[tid] - v;   // exclusive
    if (tid == 127) bsums[nb] = sm[127];      // grand total (== E)
}

__global__ void scan3_kernel(int* __restrict__ rp, const int* __restrict__ bsums,
                             int n, int* __restrict__ cursor, int nb) {
    int g = blockIdx.x * blockDim.x + threadIdx.x;
    if (g < n) {
        int r = rp[g] + bsums[g >> 10];
        rp[g] = r;
        cursor[g] = r;
    }
    if (g == 0) rp[n] = bsums[nb];
}

// bucket-fill: src grouped by dst.
// XCD-region confinement: region = blockIdx & 7 maps to one XCD (round-robin
// dispatch heuristic); each region's ssorted window is ~1.6 MB < 4 MB XCD L2,
// so scattered 4B stores accumulate in that L2 and each line writes back once
// (round-2 profile: 196 MB HBM writeback for a 12.8 MB array = 16x amp).
// Correctness does NOT depend on the XCD mapping (any wg may handle any region).
__global__ __launch_bounds__(256) void fill_kernel(const int* __restrict__ src,
                                                   const int* __restrict__ dst, int E,
                                                   int* __restrict__ cursor,
                                                   int* __restrict__ ssorted) {
    int region = blockIdx.x & (NREG - 1);
    int lo = region * REG_NODES;
    int hi = lo + REG_NODES;
    int wg  = blockIdx.x >> 3;         // workgroup index within region
    int nwg = gridDim.x >> 3;          // workgroups per region
    int i = wg * blockDim.x + threadIdx.x;
    int stride = nwg * blockDim.x;
    for (int e = i; e < E; e += stride) {
        int d = dst[e];
        if (d >= lo && d < hi) {
            int p = atomicAdd(&cursor[d], 1);
            ssorted[p] = src[e];
        }
    }
}

// ---------------- GEMM: C[N,128] = (A[N,128] @ W[128,128] + bias) * rowscale[r] ----
// rowscale (dinv) fused into epilogue: pre-scales h rows by deg^{-1/2}[src] so the
// gather inner loop needs no per-edge weights at all.
__global__ __launch_bounds__(256) void gemm_kernel(const float* __restrict__ A,
                                                   const float* __restrict__ W,
                                                   const float* __restrict__ bias,
                                                   const float* __restrict__ rowscale,
                                                   float* __restrict__ C) {
    __shared__ float As[32][128];
    int tid = threadIdx.x;
    size_t r0 = (size_t)blockIdx.x * 32;

    const float4* Ap = (const float4*)(A + r0 * D);
    float4* Asp = (float4*)&As[0][0];
#pragma unroll
    for (int i = 0; i < 4; ++i) Asp[tid + 256 * i] = Ap[tid + 256 * i];
    __syncthreads();

    int c4 = tid & 31;   // float4 column group
    int rb = tid >> 5;   // 0..7
    float4 bv = ((const float4*)bias)[c4];
    float4 acc[4];
#pragma unroll
    for (int j = 0; j < 4; ++j) acc[j] = bv;

    for (int k4 = 0; k4 < 32; ++k4) {
        float4 w0 = ((const float4*)(W + (k4 * 4 + 0) * D))[c4];
        float4 w1 = ((const float4*)(W + (k4 * 4 + 1) * D))[c4];
        float4 w2 = ((const float4*)(W + (k4 * 4 + 2) * D))[c4];
        float4 w3 = ((const float4*)(W + (k4 * 4 + 3) * D))[c4];
#pragma unroll
        for (int j = 0; j < 4; ++j) {
            float4 xv = *(const float4*)(&As[rb + 8 * j][k4 * 4]);
            acc[j].x += xv.x * w0.x + xv.y * w1.x + xv.z * w2.x + xv.w * w3.x;
            acc[j].y += xv.x * w0.y + xv.y * w1.y + xv.z * w2.y + xv.w * w3.y;
            acc[j].z += xv.x * w0.z + xv.y * w1.z + xv.z * w2.z + xv.w * w3.z;
            acc[j].w += xv.x * w0.w + xv.y * w1.w + xv.z * w2.w + xv.w * w3.w;
        }
    }
#pragma unroll
    for (int j = 0; j < 4; ++j) {
        float sc = rowscale[r0 + rb + 8 * j];   // broadcast within wave (same row)
        acc[j].x *= sc; acc[j].y *= sc; acc[j].z *= sc; acc[j].w *= sc;
        *((float4*)(C + (r0 + rb + 8 * j) * D) + c4) = acc[j];
    }
}

// ---------------- gather-sum conv ----------------
// h rows are pre-scaled by dinv[src] (gemm epilogue), so:
//   out[v] = (base ? base[v] : 0) + dinv[v]*s * sum_{e in CSR[v]} h[src_e]
// One wave per node; lane owns float2 of the 128-wide row. Edge indices are
// batch-loaded 64-at-a-time (coalesced) and broadcast via __shfl; row loads
// unrolled x8 for memory-level parallelism (loop is pure load+add).
__global__ __launch_bounds__(256) void gather_kernel(const float* __restrict__ h,
                                                     const int* __restrict__ ssorted,
                                                     const int* __restrict__ rp,
                                                     const float* __restrict__ dinv,
                                                     const float* __restrict__ base,
                                                     float* __restrict__ out,
                                                     const int* __restrict__ sp, int n) {
    int v = blockIdx.x * 4 + (threadIdx.x >> 6);
    if (v >= n) return;
    int lane = threadIdx.x & 63;
    float sf = (float)sp[0];
    int beg = rp[v], end = rp[v + 1];
    float dv = dinv[v] * sf;
    float ax = 0.0f, ay = 0.0f;

    int e = beg;
    while (e < end) {
        int cnt = end - e;
        if (cnt > 64) cnt = 64;
        int idx = (lane < cnt) ? ssorted[e + lane] : 0;   // coalesced batch load

        int j = 0;
        for (; j + 7 < cnt; j += 8) {
            int s0 = __shfl(idx, j + 0), s1 = __shfl(idx, j + 1);
            int s2 = __shfl(idx, j + 2), s3 = __shfl(idx, j + 3);
            int s4 = __shfl(idx, j + 4), s5 = __shfl(idx, j + 5);
            int s6 = __shfl(idx, j + 6), s7 = __shfl(idx, j + 7);
            float2 h0 = *(const float2*)(h + (size_t)s0 * D + lane * 2);
            float2 h1 = *(const float2*)(h + (size_t)s1 * D + lane * 2);
            float2 h2 = *(const float2*)(h + (size_t)s2 * D + lane * 2);
            float2 h3 = *(const float2*)(h + (size_t)s3 * D + lane * 2);
            float2 h4 = *(const float2*)(h + (size_t)s4 * D + lane * 2);
            float2 h5 = *(const float2*)(h + (size_t)s5 * D + lane * 2);
            float2 h6 = *(const float2*)(h + (size_t)s6 * D + lane * 2);
            float2 h7 = *(const float2*)(h + (size_t)s7 * D + lane * 2);
            ax += ((h0.x + h1.x) + (h2.x + h3.x)) + ((h4.x + h5.x) + (h6.x + h7.x));
            ay += ((h0.y + h1.y) + (h2.y + h3.y)) + ((h4.y + h5.y) + (h6.y + h7.y));
        }
        for (; j + 3 < cnt; j += 4) {
            int s0 = __shfl(idx, j + 0), s1 = __shfl(idx, j + 1);
            int s2 = __shfl(idx, j + 2), s3 = __shfl(idx, j + 3);
            float2 h0 = *(const float2*)(h + (size_t)s0 * D + lane * 2);
            float2 h1 = *(const float2*)(h + (size_t)s1 * D + lane * 2);
            float2 h2 = *(const float2*)(h + (size_t)s2 * D + lane * 2);
            float2 h3 = *(const float2*)(h + (size_t)s3 * D + lane * 2);
            ax += (h0.x + h1.x) + (h2.x + h3.x);
            ay += (h0.y + h1.y) + (h2.y + h3.y);
        }
        for (; j < cnt; ++j) {
            int s = __shfl(idx, j);
            float2 hv = *(const float2*)(h + (size_t)s * D + lane * 2);
            ax += hv.x;
            ay += hv.y;
        }
        e += cnt;
    }

    ax *= dv;
    ay *= dv;
    size_t o = (size_t)v * D + lane * 2;
    if (base) {
        float2 b2 = *(const float2*)(base + o);
        ax += b2.x;
        ay += b2.y;
    }
    *(float2*)(out + o) = make_float2(ax, ay);
}

// ---------------- launch ----------------
extern "C" void kernel_launch(void* const* d_in, const int* in_sizes, int n_in,
                              void* d_out, int out_size, void* d_ws, size_t ws_size,
                              hipStream_t stream) {
    const float* X  = (const float*)d_in[0];
    const float* W1 = (const float*)d_in[1];
    const float* b1 = (const float*)d_in[2];
    const float* W2 = (const float*)d_in[3];
    const float* b2 = (const float*)d_in[4];
    const int*   ei = (const int*)d_in[5];
    const int*   sp = (const int*)d_in[6];

    const int N = NN;
    const int E = in_sizes[5] / 2;
    const int* src = ei;
    const int* dst = ei + E;

    char* ws = (char*)d_ws;
    size_t off = 0;
    auto alloc = [&](size_t bytes) -> void* {
        void* p = ws + off;
        off += (bytes + 255) / 256 * 256;
        return p;
    };
    int*   deg    = (int*)  alloc((size_t)N * 4);
    float* dinv   = (float*)alloc((size_t)N * 4);
    int*   rp     = (int*)  alloc((size_t)(N + 1) * 4);
    int*   cursor = (int*)  alloc((size_t)N * 4);
    int*   bsums  = (int*)  alloc(256 * 4);
    int*   ssort  = (int*)  alloc((size_t)E * 4);
    float* h      = (float*)alloc((size_t)N * D * 4);
    float* x      = (float*)alloc((size_t)N * D * 4);
    float* out    = (float*)d_out;

    const int nb = (N + 1023) / 1024;  // 98

    zero_int_kernel<<<(N + 255) / 256, 256, 0, stream>>>(deg, N);
    hist_kernel<<<2048, 256, 0, stream>>>(dst, E, deg);
    dinv_kernel<<<(N + 255) / 256, 256, 0, stream>>>(deg, dinv, N);
    scan1_kernel<<<nb, 1024, 0, stream>>>(deg, N, rp, bsums);
    scan2_kernel<<<1, 128, 0, stream>>>(bsums, nb);
    scan3_kernel<<<(N + 255) / 256, 256, 0, stream>>>(rp, bsums, N, cursor, nb);
    fill_kernel<<<2048, 256, 0, stream>>>(src, dst, E, cursor, ssort);

    gemm_kernel<<<N / 32, 256, 0, stream>>>(X, W1, b1, dinv, h);
    gather_kernel<<<(N + 3) / 4, 256, 0, stream>>>(h, ssort, rp, dinv, nullptr, x, sp, N);
    gemm_kernel<<<N / 32, 256, 0, stream>>>(x, W2, b2, dinv, h);
    gather_kernel<<<(N + 3) / 4, 256, 0, stream>>>(h, ssort, rp, dinv, x, out, sp, N);
}

// Round 8
// 727.713 us; speedup vs baseline: 1.5556x; 1.3245x over previous
//
#include <hip/hip_runtime.h>
#include <cstdint>
#include <cstddef>

#define NN 100000   // N_NODES
#define D  128
#define NREG 8          // scatter regions == XCDs
#define REG_NODES 12500 // NN / NREG

// ---------------- bf16 helpers (h is stored bf16: halves gather traffic; 25.6 MB
// working set -> per-XCD reuse gap 3.2 MB < 4 MB L2, so hit rate improves too) ----
__device__ __forceinline__ unsigned short f2bf(float f) {
    unsigned u = __float_as_uint(f);
    unsigned r = (u + 0x7fffu + ((u >> 16) & 1u)) >> 16;   // round-to-nearest-even
    return (unsigned short)r;
}
__device__ __forceinline__ float bf_lo(unsigned v) { return __uint_as_float(v << 16); }
__device__ __forceinline__ float bf_hi(unsigned v) { return __uint_as_float(v & 0xffff0000u); }

// ---------------- utility ----------------
__global__ void zero_int_kernel(int* __restrict__ p, int n) {
    int i = blockIdx.x * blockDim.x + threadIdx.x;
    if (i < n) p[i] = 0;
}

// deg[dst]++ histogram
__global__ void hist_kernel(const int* __restrict__ dst, int E, int* __restrict__ deg) {
    int i = blockIdx.x * blockDim.x + threadIdx.x;
    int stride = gridDim.x * blockDim.x;
    for (int e = i; e < E; e += stride)
        atomicAdd(&deg[dst[e]], 1);
}

__global__ void dinv_kernel(const int* __restrict__ deg, float* __restrict__ dinv, int n) {
    int i = blockIdx.x * blockDim.x + threadIdx.x;
    if (i < n) {
        int d = deg[i];
        dinv[i] = (d > 0) ? (1.0f / sqrtf((float)d)) : 0.0f;
    }
}

// ---------------- prefix scan (3 stages) ----------------
__global__ __launch_bounds__(1024) void scan1_kernel(const int* __restrict__ deg, int n,
                                                     int* __restrict__ excl,
                                                     int* __restrict__ bsums) {
    __shared__ int sm[1024];
    int tid = threadIdx.x;
    int g = blockIdx.x * 1024 + tid;
    int v = (g < n) ? deg[g] : 0;
    sm[tid] = v;
    __syncthreads();
    for (int off = 1; off < 1024; off <<= 1) {
        int t = (tid >= off) ? sm[tid - off] : 0;
        __syncthreads();
        sm[tid] += t;
        __syncthreads();
    }
    if (g < n) excl[g] = sm[tid] - v;
    if (tid == 1023) bsums[blockIdx.x] = sm[1023];
}

__global__ void scan2_kernel(int* __restrict__ bsums, int nb) {
    __shared__ int sm[128];
    int tid = threadIdx.x;
    int v = (tid < nb) ? bsums[tid] : 0;
    sm[tid] = v;
    __syncthreads();
    for (int off = 1; off < 128; off <<= 1) {
        int t = (tid >= off) ? sm[tid - off] : 0;
        __syncthreads();
        sm[tid] += t;
        __syncthreads();
    }
    if (tid < nb) bsums[tid] = sm[tid] - v;   // exclusive
    if (tid == 127) bsums[nb] = sm[127];      // grand total (== E)
}

__global__ void scan3_kernel(int* __restrict__ rp, const int* __restrict__ bsums,
                             int n, int* __restrict__ cursor, int nb) {
    int g = blockIdx.x * blockDim.x + threadIdx.x;
    if (g < n) {
        int r = rp[g] + bsums[g >> 10];
        rp[g] = r;
        cursor[g] = r;
    }
    if (g == 0) rp[n] = bsums[nb];
}

// bucket-fill: src grouped by dst. XCD-region confinement (round-2 profile showed
// 196 MB writeback for a 12.8 MB array = 16x amp; region window 1.6 MB < 4 MB L2).
// Correctness does NOT depend on the XCD mapping.
__global__ __launch_bounds__(256) void fill_kernel(const int* __restrict__ src,
                                                   const int* __restrict__ dst, int E,
                                                   int* __restrict__ cursor,
                                                   int* __restrict__ ssorted) {
    int region = blockIdx.x & (NREG - 1);
    int lo = region * REG_NODES;
    int hi = lo + REG_NODES;
    int wg  = blockIdx.x >> 3;
    int nwg = gridDim.x >> 3;
    int i = wg * blockDim.x + threadIdx.x;
    int stride = nwg * blockDim.x;
    for (int e = i; e < E; e += stride) {
        int d = dst[e];
        if (d >= lo && d < hi) {
            int p = atomicAdd(&cursor[d], 1);
            ssorted[p] = src[e];
        }
    }
}

// ---------------- GEMM: Hbf16[N,128] = ((A[N,128] @ W + bias) * rowscale[r]) ------
// f32 accumulate, dinv fused, single RNE round to bf16 at the store.
__global__ __launch_bounds__(256) void gemm_kernel(const float* __restrict__ A,
                                                   const float* __restrict__ W,
                                                   const float* __restrict__ bias,
                                                   const float* __restrict__ rowscale,
                                                   unsigned short* __restrict__ Cb) {
    __shared__ float As[32][128];
    int tid = threadIdx.x;
    size_t r0 = (size_t)blockIdx.x * 32;

    const float4* Ap = (const float4*)(A + r0 * D);
    float4* Asp = (float4*)&As[0][0];
#pragma unroll
    for (int i = 0; i < 4; ++i) Asp[tid + 256 * i] = Ap[tid + 256 * i];
    __syncthreads();

    int c4 = tid & 31;   // float4 column group
    int rb = tid >> 5;   // 0..7
    float4 bv = ((const float4*)bias)[c4];
    float4 acc[4];
#pragma unroll
    for (int j = 0; j < 4; ++j) acc[j] = bv;

    for (int k4 = 0; k4 < 32; ++k4) {
        float4 w0 = ((const float4*)(W + (k4 * 4 + 0) * D))[c4];
        float4 w1 = ((const float4*)(W + (k4 * 4 + 1) * D))[c4];
        float4 w2 = ((const float4*)(W + (k4 * 4 + 2) * D))[c4];
        float4 w3 = ((const float4*)(W + (k4 * 4 + 3) * D))[c4];
#pragma unroll
        for (int j = 0; j < 4; ++j) {
            float4 xv = *(const float4*)(&As[rb + 8 * j][k4 * 4]);
            acc[j].x += xv.x * w0.x + xv.y * w1.x + xv.z * w2.x + xv.w * w3.x;
            acc[j].y += xv.x * w0.y + xv.y * w1.y + xv.z * w2.y + xv.w * w3.y;
            acc[j].z += xv.x * w0.z + xv.y * w1.z + xv.z * w2.z + xv.w * w3.z;
            acc[j].w += xv.x * w0.w + xv.y * w1.w + xv.z * w2.w + xv.w * w3.w;
        }
    }
#pragma unroll
    for (int j = 0; j < 4; ++j) {
        float sc = rowscale[r0 + rb + 8 * j];   // broadcast within wave (same row)
        uint2 p;
        p.x = (unsigned)f2bf(acc[j].x * sc) | ((unsigned)f2bf(acc[j].y * sc) << 16);
        p.y = (unsigned)f2bf(acc[j].z * sc) | ((unsigned)f2bf(acc[j].w * sc) << 16);
        *(uint2*)(Cb + (r0 + rb + 8 * j) * D + (c4 << 2)) = p;   // 8B coalesced
    }
}

// ---------------- gather-sum conv ----------------
// h rows bf16, pre-scaled by dinv[src]:
//   out[v] = (base ? base[v] : 0) + dinv[v]*s * sum_{e in CSR[v]} h[src_e]
// One wave per node; lane owns dims (2*lane, 2*lane+1) = one u32 of 2 bf16.
// Edge indices batch-loaded 64-at-a-time, broadcast via __shfl; row loads
// unrolled x16 for memory-level parallelism (f32 accumulate).
__global__ __launch_bounds__(256) void gather_kernel(const unsigned short* __restrict__ hb,
                                                     const int* __restrict__ ssorted,
                                                     const int* __restrict__ rp,
                                                     const float* __restrict__ dinv,
                                                     const float* __restrict__ base,
                                                     float* __restrict__ out,
                                                     const int* __restrict__ sp, int n) {
    int v = blockIdx.x * 4 + (threadIdx.x >> 6);
    if (v >= n) return;
    int lane = threadIdx.x & 63;
    float sf = (float)sp[0];
    int beg = rp[v], end = rp[v + 1];
    float dv = dinv[v] * sf;
    float ax = 0.0f, ay = 0.0f;

    int e = beg;
    while (e < end) {
        int cnt = end - e;
        if (cnt > 64) cnt = 64;
        int idx = (lane < cnt) ? ssorted[e + lane] : 0;   // coalesced batch load

        int j = 0;
        for (; j + 15 < cnt; j += 16) {
            unsigned hv[16];
#pragma unroll
            for (int k = 0; k < 16; ++k) {
                int s = __shfl(idx, j + k);
                hv[k] = *(const unsigned*)(hb + (size_t)s * D + (lane << 1));
            }
#pragma unroll
            for (int k = 0; k < 16; ++k) {
                ax += bf_lo(hv[k]);
                ay += bf_hi(hv[k]);
            }
        }
        for (; j + 7 < cnt; j += 8) {
            unsigned hv[8];
#pragma unroll
            for (int k = 0; k < 8; ++k) {
                int s = __shfl(idx, j + k);
                hv[k] = *(const unsigned*)(hb + (size_t)s * D + (lane << 1));
            }
#pragma unroll
            for (int k = 0; k < 8; ++k) {
                ax += bf_lo(hv[k]);
                ay += bf_hi(hv[k]);
            }
        }
        for (; j + 3 < cnt; j += 4) {
            unsigned hv[4];
#pragma unroll
            for (int k = 0; k < 4; ++k) {
                int s = __shfl(idx, j + k);
                hv[k] = *(const unsigned*)(hb + (size_t)s * D + (lane << 1));
            }
#pragma unroll
            for (int k = 0; k < 4; ++k) {
                ax += bf_lo(hv[k]);
                ay += bf_hi(hv[k]);
            }
        }
        for (; j < cnt; ++j) {
            int s = __shfl(idx, j);
            unsigned hv = *(const unsigned*)(hb + (size_t)s * D + (lane << 1));
            ax += bf_lo(hv);
            ay += bf_hi(hv);
        }
        e += cnt;
    }

    ax *= dv;
    ay *= dv;
    size_t o = (size_t)v * D + (lane << 1);
    if (base) {
        float2 b2 = *(const float2*)(base + o);
        ax += b2.x;
        ay += b2.y;
    }
    *(float2*)(out + o) = make_float2(ax, ay);
}

// ---------------- launch ----------------
extern "C" void kernel_launch(void* const* d_in, const int* in_sizes, int n_in,
                              void* d_out, int out_size, void* d_ws, size_t ws_size,
                              hipStream_t stream) {
    const float* X  = (const float*)d_in[0];
    const float* W1 = (const float*)d_in[1];
    const float* b1 = (const float*)d_in[2];
    const float* W2 = (const float*)d_in[3];
    const float* b2 = (const float*)d_in[4];
    const int*   ei = (const int*)d_in[5];
    const int*   sp = (const int*)d_in[6];

    const int N = NN;
    const int E = in_sizes[5] / 2;
    const int* src = ei;
    const int* dst = ei + E;

    char* ws = (char*)d_ws;
    size_t off = 0;
    auto alloc = [&](size_t bytes) -> void* {
        void* p = ws + off;
        off += (bytes + 255) / 256 * 256;
        return p;
    };
    int*            deg    = (int*)  alloc((size_t)N * 4);
    float*          dinv   = (float*)alloc((size_t)N * 4);
    int*            rp     = (int*)  alloc((size_t)(N + 1) * 4);
    int*            cursor = (int*)  alloc((size_t)N * 4);
    int*            bsums  = (int*)  alloc(256 * 4);
    int*            ssort  = (int*)  alloc((size_t)E * 4);
    unsigned short* hb     = (unsigned short*)alloc((size_t)N * D * 2);
    float*          x      = (float*)alloc((size_t)N * D * 4);
    float*          out    = (float*)d_out;

    const int nb = (N + 1023) / 1024;  // 98

    zero_int_kernel<<<(N + 255) / 256, 256, 0, stream>>>(deg, N);
    hist_kernel<<<2048, 256, 0, stream>>>(dst, E, deg);
    dinv_kernel<<<(N + 255) / 256, 256, 0, stream>>>(deg, dinv, N);
    scan1_kernel<<<nb, 1024, 0, stream>>>(deg, N, rp, bsums);
    scan2_kernel<<<1, 128, 0, stream>>>(bsums, nb);
    scan3_kernel<<<(N + 255) / 256, 256, 0, stream>>>(rp, bsums, N, cursor, nb);
    fill_kernel<<<2048, 256, 0, stream>>>(src, dst, E, cursor, ssort);

    gemm_kernel<<<N / 32, 256, 0, stream>>>(X, W1, b1, dinv, hb);
    gather_kernel<<<(N + 3) / 4, 256, 0, stream>>>(hb, ssort, rp, dinv, nullptr, x, sp, N);
    gemm_kernel<<<N / 32, 256, 0, stream>>>(x, W2, b2, dinv, hb);
    gather_kernel<<<(N + 3) / 4, 256, 0, stream>>>(hb, ssort, rp, dinv, x, out, sp, N);
}